// Round 8
// baseline (254.393 us; speedup 1.0000x reference)
//
#include <hip/hip_runtime.h>
#include <hip/hip_bf16.h>
#include <stdint.h>

// B=8, N=1024, D=256, fp32 in/out.
// R8: mega v4 — logits live in LDS (col-major fp32, stride 18), not registers.
// Per col-group acc = 8 VGPRs; A-frags preloaded once (128 VGPRs); B loads
// stream with no barriers -> compiler can pipeline. Softmax/blend/entropy/
// route from LDS; PV reads selected-branch probs per-lane from LDS.
// R5: 256 acc VGPR, 1 w/SIMD, 97us. R6: 128 acc, latency-bound, 117us.
// R7: launch_bounds(512,4) spilled (VGPR=64, WRITE 63MB), 131us.

#define NB 8
#define NN_ 1024
#define ND 256

typedef __bf16 bf16x8 __attribute__((ext_vector_type(8)));
typedef __bf16 bf16x4 __attribute__((ext_vector_type(4)));
typedef float f32x4 __attribute__((ext_vector_type(4)));

#define LSTRIDE 18           // words per column (16 rows + 2 pad, even => b64 ok)
#define LBR (1024 * LSTRIDE) // per-branch region in words

// ---------------- async global->LDS (16B per lane) -- used by xs mgemm ------
__device__ inline void gl_lds(const __bf16* g, __bf16* l) {
    auto gp = (const __attribute__((address_space(1))) uint32_t*)(uintptr_t)g;
    auto lp = (__attribute__((address_space(3))) uint32_t*)(uintptr_t)l;
    __builtin_amdgcn_global_load_lds(gp, lp, 16, 0, 0);
}

// ---------------- reductions ----------------
__device__ inline float wred_sum(float v) {
#pragma unroll
    for (int o = 32; o; o >>= 1) v += __shfl_xor(v, o, 64);
    return v;
}
__device__ inline float wred_max(float v) {
#pragma unroll
    for (int o = 32; o; o >>= 1) v = fmaxf(v, __shfl_xor(v, o, 64));
    return v;
}

// ---------------- fused prep: pos softmax | x split | y prep | build M ------
__global__ __launch_bounds__(256) void prep_kernel(
    const float* __restrict__ coords, const float* __restrict__ pos_emb,
    const float* __restrict__ p_temp, const float* __restrict__ x,
    const float* __restrict__ y, const float* __restrict__ U,
    const float* __restrict__ S1, const float* __restrict__ S2,
    float* __restrict__ posS, __bf16* __restrict__ Xh, __bf16* __restrict__ Xl,
    __bf16* __restrict__ yt, __bf16* __restrict__ Yh, __bf16* __restrict__ Yl,
    __bf16* __restrict__ Mh, __bf16* __restrict__ Ml) {
    __shared__ char sm[9216 + 64];
    const int bid = blockIdx.x;
    const int tid = threadIdx.x;

    if (bid < 1024) {
        float* red = (float*)sm;
        const int n = bid;
        const float pt = -fabsf(p_temp[0]);
        float pe[6];
#pragma unroll
        for (int c = 0; c < 6; ++c) pe[c] = pos_emb[n * 6 + c];
        const float* cr = coords + (long)n * NN_ * 6;
        float l[4];
#pragma unroll
        for (int j = 0; j < 4; ++j) {
            const int m = j * 256 + tid;
            const float2* cp = (const float2*)(cr + (long)m * 6);
            float2 c0 = cp[0], c1 = cp[1], c2 = cp[2];
            l[j] = pt * (c0.x * pe[0] + c0.y * pe[1] + c1.x * pe[2] +
                         c1.y * pe[3] + c2.x * pe[4] + c2.y * pe[5]);
        }
        float mx = fmaxf(fmaxf(l[0], l[1]), fmaxf(l[2], l[3]));
        mx = wred_max(mx);
        __syncthreads();
        if ((tid & 63) == 0) red[tid >> 6] = mx;
        __syncthreads();
        mx = fmaxf(fmaxf(red[0], red[1]), fmaxf(red[2], red[3]));
        float e[4], s = 0.f;
#pragma unroll
        for (int j = 0; j < 4; ++j) { e[j] = __expf(l[j] - mx); s += e[j]; }
        s = wred_sum(s);
        __syncthreads();
        if ((tid & 63) == 0) red[4 + (tid >> 6)] = s;
        __syncthreads();
        s = red[4] + red[5] + red[6] + red[7];
        const float inv = 1.f / s;
#pragma unroll
        for (int j = 0; j < 4; ++j)
            posS[(long)n * NN_ + j * 256 + tid] = e[j] * inv;
    } else if (bid < 1536) {
        const int n4 = NB * NN_ * ND / 4;
        int i = (bid - 1024) * 256 + tid;
        for (; i < n4; i += 512 * 256) {
            float4 v = ((const float4*)x)[i];
            bf16x4 h, l;
            h[0] = (__bf16)v.x; l[0] = (__bf16)(v.x - (float)h[0]);
            h[1] = (__bf16)v.y; l[1] = (__bf16)(v.y - (float)h[1]);
            h[2] = (__bf16)v.z; l[2] = (__bf16)(v.z - (float)h[2]);
            h[3] = (__bf16)v.w; l[3] = (__bf16)(v.w - (float)h[3]);
            ((bf16x4*)Xh)[i] = h;
            ((bf16x4*)Xl)[i] = l;
        }
    } else if (bid < 2048) {
        __bf16 (*t)[72] = (__bf16(*)[72])sm;
        const int rem = bid - 1536;
        const int b = rem >> 6;
        const int m0 = (rem & 15) * 64, d0 = ((rem >> 4) & 3) * 64;
        const int c = tid & 15;
        const int r = tid >> 4;
#pragma unroll
        for (int p = 0; p < 4; ++p) {
            const int row = r + p * 16;
            const long gi = ((long)b * NN_ + m0 + row) * ND + d0 + c * 4;
            float4 v = *(const float4*)(y + gi);
            bf16x4 h, l;
            h[0] = (__bf16)v.x; l[0] = (__bf16)(v.x - (float)h[0]);
            h[1] = (__bf16)v.y; l[1] = (__bf16)(v.y - (float)h[1]);
            h[2] = (__bf16)v.z; l[2] = (__bf16)(v.z - (float)h[2]);
            h[3] = (__bf16)v.w; l[3] = (__bf16)(v.w - (float)h[3]);
            *(bf16x4*)(Yh + gi) = h;
            *(bf16x4*)(Yl + gi) = l;
            t[c * 4 + 0][row] = h[0]; t[c * 4 + 1][row] = h[1];
            t[c * 4 + 2][row] = h[2]; t[c * 4 + 3][row] = h[3];
        }
        __syncthreads();
#pragma unroll
        for (int p = 0; p < 4; ++p) {
            const int d = r + p * 16;
            bf16x4 o;
            o[0] = t[d][c * 4 + 0]; o[1] = t[d][c * 4 + 1];
            o[2] = t[d][c * 4 + 2]; o[3] = t[d][c * 4 + 3];
            *(bf16x4*)(yt + ((long)b * ND + d0 + d) * NN_ + m0 + c * 4) = o;
        }
    } else {
        const int n = bid - 2048, j = tid;
        float a1 = 0.f, a2 = 0.f;
        for (int c = 0; c < ND; ++c) {
            const float un = U[c * ND + n];
            const float uj = U[c * ND + j];
            a1 = fmaf(fabsf(S1[c]) * un, uj, a1);
            a2 = fmaf(fabsf(S2[c]) * un, uj, a2);
        }
        const __bf16 h1 = (__bf16)a1, h2 = (__bf16)a2;
        Mh[n * ND + j] = h1;           Ml[n * ND + j] = (__bf16)(a1 - (float)h1);
        Mh[65536 + n * ND + j] = h2;   Ml[65536 + n * ND + j] = (__bf16)(a2 - (float)h2);
    }
}

// ---------------- MFMA GEMM (xs = x @ M_k), global_load_lds staged ----------
__global__ __launch_bounds__(256) void mgemm(
    const __bf16* __restrict__ Ah, const __bf16* __restrict__ Al,
    const __bf16* __restrict__ Bh, const __bf16* __restrict__ Bl,
    __bf16* __restrict__ Ch, __bf16* __restrict__ Cl,
    int M, int N, int K, long sB1, long sC) {
    constexpr int BM = 128, BK = 32, BN = 64;
    __shared__ __bf16 As[2 * BM * BK];
    __shared__ __bf16 Bs[2 * BN * BK];

    const int z = blockIdx.z;
    Bh += (long)z * sB1; Bl += (long)z * sB1;

    const int tid = threadIdx.x;
    const int bm = blockIdx.y * BM, bn = blockIdx.x * BN;
    const int wave = tid >> 6, lane = tid & 63;
    const int wm = wave >> 1, wn = wave & 1;
    const int quad = lane >> 4, l16 = lane & 15;

    f32x4 acc[4][2];
#pragma unroll
    for (int i = 0; i < 4; ++i)
#pragma unroll
        for (int j = 0; j < 2; ++j) acc[i][j] = (f32x4){0.f, 0.f, 0.f, 0.f};

    const int srow = lane >> 2;
    const int slot = lane & 3;

    for (int k0 = 0; k0 < K; k0 += BK) {
        __syncthreads();
#pragma unroll
        for (int i = 0; i < 2; ++i) {
            const int r0 = wave * 32 + i * 16;
            const int row = r0 + srow;
            const int chunk = slot ^ ((row >> 1) & 3);
            const long g = (long)(bm + row) * K + k0 + chunk * 8;
            gl_lds(Ah + g, &As[r0 * 32]);
            gl_lds(Al + g, &As[BM * BK + r0 * 32]);
        }
        {
            const int r0 = wave * 16;
            const int row = r0 + srow;
            const int chunk = slot ^ ((row >> 1) & 3);
            const long g = (long)(bn + row) * K + k0 + chunk * 8;
            gl_lds(Bh + g, &Bs[r0 * 32]);
            gl_lds(Bl + g, &Bs[BN * BK + r0 * 32]);
        }
        __syncthreads();

        bf16x8 a_h[4], a_l[4], b_h[2], b_l[2];
#pragma unroll
        for (int mi = 0; mi < 4; ++mi) {
            const int row = wm * 64 + mi * 16 + l16;
            const int off = row * 32 + ((quad ^ ((row >> 1) & 3)) * 8);
            a_h[mi] = *(const bf16x8*)&As[off];
            a_l[mi] = *(const bf16x8*)&As[BM * BK + off];
        }
#pragma unroll
        for (int ni = 0; ni < 2; ++ni) {
            const int row = wn * 32 + ni * 16 + l16;
            const int off = row * 32 + ((quad ^ ((row >> 1) & 3)) * 8);
            b_h[ni] = *(const bf16x8*)&Bs[off];
            b_l[ni] = *(const bf16x8*)&Bs[BN * BK + off];
        }
#pragma unroll
        for (int mi = 0; mi < 4; ++mi)
#pragma unroll
            for (int ni = 0; ni < 2; ++ni) {
                acc[mi][ni] = __builtin_amdgcn_mfma_f32_16x16x32_bf16(
                    a_h[mi], b_h[ni], acc[mi][ni], 0, 0, 0);
                acc[mi][ni] = __builtin_amdgcn_mfma_f32_16x16x32_bf16(
                    a_h[mi], b_l[ni], acc[mi][ni], 0, 0, 0);
                acc[mi][ni] = __builtin_amdgcn_mfma_f32_16x16x32_bf16(
                    a_l[mi], b_h[ni], acc[mi][ni], 0, 0, 0);
            }
    }

    Ch += (long)z * sC; Cl += (long)z * sC;
#pragma unroll
    for (int mi = 0; mi < 4; ++mi) {
        const int row0 = bm + wm * 64 + mi * 16 + quad * 4;
#pragma unroll
        for (int ni = 0; ni < 2; ++ni) {
            const int col = bn + wn * 32 + ni * 16 + l16;
#pragma unroll
            for (int r = 0; r < 4; ++r) {
                const float v = acc[mi][ni][r];
                const long idx = (long)(row0 + r) * N + col;
                const __bf16 h = (__bf16)v;
                Ch[idx] = h;
                Cl[idx] = (__bf16)(v - (float)h);
            }
        }
    }
}

// ---------------- MEGA v4: logits in LDS --------------------------------
// Block 256 thr (4 waves); b = blk&7; rows n0..n0+15. Wave w owns cols
// [w*256, w*256+256) in 16 groups of 16. A-frags preloaded (128 VGPR).
// LDS: Ls[2][1024][18] fp32 logits/probs (col-major) + redA[512] + selv[16].
__global__ __launch_bounds__(256, 1) void mega_kernel(
    const __bf16* __restrict__ XSh, const __bf16* __restrict__ XSl,
    const __bf16* __restrict__ Yh, const __bf16* __restrict__ Yl,
    const __bf16* __restrict__ yt, const float* __restrict__ pos,
    const float* __restrict__ gating, const float* __restrict__ h_temp,
    float* __restrict__ heat, float* __restrict__ out) {
    extern __shared__ float smem[];
    float* Ls   = smem;                 // 2 * 1024 * 18 = 36864 floats
    float* redA = smem + 2 * LBR;       // 512
    float* selv = redA + 512;           // 16

    const int b  = blockIdx.x & 7;
    const int n0 = (blockIdx.x >> 3) * 16;
    const int tid = threadIdx.x;
    const int wave = tid >> 6, lane = tid & 63;
    const int quad = lane >> 4, l16 = lane & 15;
    const int wcol = wave * 256;
    const long BNDe = (long)NB * NN_ * ND;

    // ---- preload A fragments: 2 br x 8 k0, hi+lo (128 VGPRs) ----
    const __bf16* Ahp = XSh + ((long)b * NN_ + n0) * ND;
    const __bf16* Alp = XSl + ((long)b * NN_ + n0) * ND;
    bf16x8 afh[2][8], afl[2][8];
#pragma unroll
    for (int br = 0; br < 2; ++br)
#pragma unroll
        for (int k0 = 0; k0 < 8; ++k0) {
            const long o = (long)br * BNDe + (long)l16 * ND + k0 * 32 + quad * 8;
            afh[br][k0] = *(const bf16x8*)(Ahp + o);
            afl[br][k0] = *(const bf16x8*)(Alp + o);
        }

    // ---- G phase: per 16-col group, acc -> LDS ----
    const __bf16* Bhp = Yh + ((long)b * NN_ + wcol) * ND;
    const __bf16* Blp = Yl + ((long)b * NN_ + wcol) * ND;
#pragma unroll 2
    for (int ni = 0; ni < 16; ++ni) {
        f32x4 P0 = {0,0,0,0}, Q0 = {0,0,0,0}, P1 = {0,0,0,0}, Q1 = {0,0,0,0};
        const long cb = (long)(ni * 16 + l16) * ND + quad * 8;
#pragma unroll
        for (int k0 = 0; k0 < 8; ++k0) {
            bf16x8 bh = *(const bf16x8*)(Bhp + cb + k0 * 32);
            bf16x8 bl = *(const bf16x8*)(Blp + cb + k0 * 32);
            P0 = __builtin_amdgcn_mfma_f32_16x16x32_bf16(afh[0][k0], bh, P0, 0, 0, 0);
            Q0 = __builtin_amdgcn_mfma_f32_16x16x32_bf16(afh[0][k0], bl, Q0, 0, 0, 0);
            Q0 = __builtin_amdgcn_mfma_f32_16x16x32_bf16(afl[0][k0], bh, Q0, 0, 0, 0);
            P1 = __builtin_amdgcn_mfma_f32_16x16x32_bf16(afh[1][k0], bh, P1, 0, 0, 0);
            Q1 = __builtin_amdgcn_mfma_f32_16x16x32_bf16(afh[1][k0], bl, Q1, 0, 0, 0);
            Q1 = __builtin_amdgcn_mfma_f32_16x16x32_bf16(afl[1][k0], bh, Q1, 0, 0, 0);
        }
        const int col = wcol + ni * 16 + l16;
        float2* d0 = (float2*)&Ls[col * LSTRIDE + quad * 4];
        float2* d1 = (float2*)&Ls[LBR + col * LSTRIDE + quad * 4];
        d0[0] = make_float2((P0[0] + Q0[0]) * 0.0625f, (P0[1] + Q0[1]) * 0.0625f);
        d0[1] = make_float2((P0[2] + Q0[2]) * 0.0625f, (P0[3] + Q0[3]) * 0.0625f);
        d1[0] = make_float2((P1[0] + Q1[0]) * 0.0625f, (P1[1] + Q1[1]) * 0.0625f);
        d1[1] = make_float2((P1[2] + Q1[2]) * 0.0625f, (P1[3] + Q1[3]) * 0.0625f);
    }
    __syncthreads();

    // ---- S phase: thread (r, cc) owns row r, cols cc*64..+64 ----
    const int r = tid & 15, cc = tid >> 4;
    const int c0 = cc * 64;

    // pass 1: max
    float m0 = -3.4e38f, m1 = -3.4e38f;
    for (int j = 0; j < 64; ++j) {
        m0 = fmaxf(m0, Ls[(c0 + j) * LSTRIDE + r]);
        m1 = fmaxf(m1, Ls[LBR + (c0 + j) * LSTRIDE + r]);
    }
    redA[cc * 16 + r] = m0;
    redA[256 + cc * 16 + r] = m1;
    __syncthreads();
    m0 = redA[r]; m1 = redA[256 + r];
#pragma unroll
    for (int c = 1; c < 16; ++c) {
        m0 = fmaxf(m0, redA[c * 16 + r]);
        m1 = fmaxf(m1, redA[256 + c * 16 + r]);
    }
    __syncthreads();

    // pass 2: exp in place + sum
    float s0 = 0.f, s1 = 0.f;
    for (int j = 0; j < 64; ++j) {
        float* p0 = &Ls[(c0 + j) * LSTRIDE + r];
        float* p1 = &Ls[LBR + (c0 + j) * LSTRIDE + r];
        const float e0 = __expf(*p0 - m0); *p0 = e0; s0 += e0;
        const float e1 = __expf(*p1 - m1); *p1 = e1; s1 += e1;
    }
    redA[cc * 16 + r] = s0;
    redA[256 + cc * 16 + r] = s1;
    __syncthreads();
    s0 = redA[r]; s1 = redA[256 + r];
#pragma unroll
    for (int c = 1; c < 16; ++c) {
        s0 += redA[c * 16 + r];
        s1 += redA[256 + c * 16 + r];
    }
    const float inv0 = 1.f / s0, inv1 = 1.f / s1;
    __syncthreads();

    // pass 3: blend + entropy, probs in place
    const float g = 1.f / (1.f + __expf(-gating[0]));
    const float cg = 1.f - g;
    const float* pr = pos + (long)(n0 + r) * NN_ + c0;
    float e0a = 0.f, e1a = 0.f;
    for (int j = 0; j < 64; ++j) {
        float* p0 = &Ls[(c0 + j) * LSTRIDE + r];
        float* p1 = &Ls[LBR + (c0 + j) * LSTRIDE + r];
        const float pv = pr[j];
        const float a0 = cg * (*p0) * inv0 + g * pv;
        const float a1 = cg * (*p1) * inv1 + g * pv;
        *p0 = a0; *p1 = a1;
        e0a -= a0 * __logf(a0 + 1e-8f);
        e1a -= a1 * __logf(a1 + 1e-8f);
    }
    redA[cc * 16 + r] = e0a;
    redA[256 + cc * 16 + r] = e1a;
    __syncthreads();
    if (tid < 16) {
        float E0 = 0.f, E1 = 0.f;
#pragma unroll
        for (int c = 0; c < 16; ++c) {
            E0 += redA[c * 16 + tid];
            E1 += redA[256 + c * 16 + tid];
        }
        const float ht = h_temp[0];
        const float hm0 = 2.f - 2.f / (1.f + __expf(-ht * E0));
        const float hm1 = 2.f - 2.f / (1.f + __expf(-ht * E1));
        const bool fg = (hm0 >= hm1);
        selv[tid] = fg ? 0.f : 1.f;
        heat[(long)b * NN_ + n0 + tid] = fg ? hm0 : hm1;
    }
    __syncthreads();

    // ---- PV phase: out[16 x 256] = P(sel, LDS) @ yt^T; wave d-slice 64 ----
    const int pbase = (selv[l16] != 0.f ? LBR : 0) + l16;  // + k*LSTRIDE
    f32x4 oacc[4];
#pragma unroll
    for (int nd = 0; nd < 4; ++nd) oacc[nd] = (f32x4){0.f, 0.f, 0.f, 0.f};
    const __bf16* Bo = yt + ((long)b * ND + wave * 64) * NN_;
    for (int k0 = 0; k0 < NN_; k0 += 32) {
        bf16x8 pa;
#pragma unroll
        for (int j = 0; j < 8; ++j)
            pa[j] = (__bf16)Ls[pbase + (k0 + quad * 8 + j) * LSTRIDE];
#pragma unroll
        for (int nd = 0; nd < 4; ++nd) {
            bf16x8 bo = *(const bf16x8*)(Bo + (long)(nd * 16 + l16) * NN_ + k0 + quad * 8);
            oacc[nd] = __builtin_amdgcn_mfma_f32_16x16x32_bf16(pa, bo, oacc[nd], 0, 0, 0);
        }
    }
#pragma unroll
    for (int nd = 0; nd < 4; ++nd)
#pragma unroll
        for (int rr = 0; rr < 4; ++rr)
            out[((long)b * NN_ + n0 + quad * 4 + rr) * ND +
                wave * 64 + nd * 16 + l16] = oacc[nd][rr];
}

extern "C" void kernel_launch(void* const* d_in, const int* in_sizes, int n_in,
                              void* d_out, int out_size, void* d_ws, size_t ws_size,
                              hipStream_t stream) {
    const float* x      = (const float*)d_in[0];
    const float* y      = (const float*)d_in[1];
    const float* coords = (const float*)d_in[2];
    const float* U      = (const float*)d_in[3];
    const float* S1p    = (const float*)d_in[4];
    const float* S2p    = (const float*)d_in[5];
    const float* gating = (const float*)d_in[6];
    const float* h_temp = (const float*)d_in[7];
    const float* p_temp = (const float*)d_in[8];
    const float* pos_emb= (const float*)d_in[9];

    float* out  = (float*)d_out;
    float* heat = out + (long)NB * NN_ * ND;

    // workspace (~41 MB)
    char* ws = (char*)d_ws;
    const long MB = 1 << 20;
    float*  pos = (float*)(ws);               // 4 MB
    __bf16* Xh  = (__bf16*)(ws + 4 * MB);     // 4 MB
    __bf16* Xl  = (__bf16*)(ws + 8 * MB);     // 4 MB
    __bf16* XSh = (__bf16*)(ws + 12 * MB);    // 8 MB [2][8192][256]
    __bf16* XSl = (__bf16*)(ws + 20 * MB);    // 8 MB
    __bf16* yt  = (__bf16*)(ws + 28 * MB);    // 4 MB [8][256][1024]
    __bf16* Yh  = (__bf16*)(ws + 32 * MB);    // 4 MB
    __bf16* Yl  = (__bf16*)(ws + 36 * MB);    // 4 MB
    __bf16* Mh  = (__bf16*)(ws + 40 * MB);    // 256 KB [2][256][256]
    __bf16* Ml  = Mh + 2 * 65536;             // 256 KB

    const long BND = (long)NB * NN_ * ND;     // 2097152

    // 1) fused prep
    prep_kernel<<<dim3(2304), 256, 0, stream>>>(
        coords, pos_emb, p_temp, x, y, U, S1p, S2p,
        pos, Xh, Xl, yt, Yh, Yl, Mh, Ml);

    // 2) xs_k = x @ M_k  (z=k) -> XS [2][8192][256]
    mgemm<<<dim3(4, 64, 2), 256, 0, stream>>>(
        Xh, Xl, Mh, Ml, XSh, XSl, NB * NN_, ND, ND, 65536, BND);

    // 3) mega: scores + softmax + blend + entropy + route + out
    const int megalds = (2 * LBR + 512 + 16) * 4;  // 149568 B
    hipFuncSetAttribute((const void*)mega_kernel,
                        hipFuncAttributeMaxDynamicSharedMemorySize, megalds);
    mega_kernel<<<dim3(512), 256, megalds, stream>>>(
        XSh, XSl, Yh, Yl, yt, pos, gating, h_temp, heat, out);

    (void)in_sizes; (void)n_in; (void)out_size; (void)ws_size;
}

// Round 9
// 216.510 us; speedup vs baseline: 1.1750x; 1.1750x over previous
//
#include <hip/hip_runtime.h>
#include <hip/hip_bf16.h>
#include <stdint.h>

// B=8, N=1024, D=256, fp32 in/out.
// R9: revert to R4 split pipeline (mega fusion failed 4x: 97/117/131/131 us —
// scores GEMM and row epilogue have incompatible occupancy/layout needs).
// 4 dispatches: prep -> xs mgemm -> scores mgemm (fp32 S, L3-resident) ->
// blendpv (wave-owns-row softmax/route + PV MFMA fused; replaces blend+out).

#define NB 8
#define NN_ 1024
#define ND 256

typedef __bf16 bf16x8 __attribute__((ext_vector_type(8)));
typedef __bf16 bf16x4 __attribute__((ext_vector_type(4)));
typedef float f32x4 __attribute__((ext_vector_type(4)));

// ---------------- async global->LDS (16B per lane) ----------------
__device__ inline void gl_lds(const __bf16* g, __bf16* l) {
    auto gp = (const __attribute__((address_space(1))) uint32_t*)(uintptr_t)g;
    auto lp = (__attribute__((address_space(3))) uint32_t*)(uintptr_t)l;
    __builtin_amdgcn_global_load_lds(gp, lp, 16, 0, 0);
}

// ---------------- reductions ----------------
__device__ inline float wred_sum(float v) {
#pragma unroll
    for (int o = 32; o; o >>= 1) v += __shfl_xor(v, o, 64);
    return v;
}
__device__ inline float wred_max(float v) {
#pragma unroll
    for (int o = 32; o; o >>= 1) v = fmaxf(v, __shfl_xor(v, o, 64));
    return v;
}

// ---------------- fused prep: pos softmax | x split | y prep | build M ------
__global__ __launch_bounds__(256) void prep_kernel(
    const float* __restrict__ coords, const float* __restrict__ pos_emb,
    const float* __restrict__ p_temp, const float* __restrict__ x,
    const float* __restrict__ y, const float* __restrict__ U,
    const float* __restrict__ S1, const float* __restrict__ S2,
    float* __restrict__ posS, __bf16* __restrict__ Xh, __bf16* __restrict__ Xl,
    __bf16* __restrict__ yt, __bf16* __restrict__ Yh, __bf16* __restrict__ Yl,
    __bf16* __restrict__ Mh, __bf16* __restrict__ Ml) {
    __shared__ char sm[9216 + 64];
    const int bid = blockIdx.x;
    const int tid = threadIdx.x;

    if (bid < 1024) {
        float* red = (float*)sm;
        const int n = bid;
        const float pt = -fabsf(p_temp[0]);
        float pe[6];
#pragma unroll
        for (int c = 0; c < 6; ++c) pe[c] = pos_emb[n * 6 + c];
        const float* cr = coords + (long)n * NN_ * 6;
        float l[4];
#pragma unroll
        for (int j = 0; j < 4; ++j) {
            const int m = j * 256 + tid;
            const float2* cp = (const float2*)(cr + (long)m * 6);
            float2 c0 = cp[0], c1 = cp[1], c2 = cp[2];
            l[j] = pt * (c0.x * pe[0] + c0.y * pe[1] + c1.x * pe[2] +
                         c1.y * pe[3] + c2.x * pe[4] + c2.y * pe[5]);
        }
        float mx = fmaxf(fmaxf(l[0], l[1]), fmaxf(l[2], l[3]));
        mx = wred_max(mx);
        __syncthreads();
        if ((tid & 63) == 0) red[tid >> 6] = mx;
        __syncthreads();
        mx = fmaxf(fmaxf(red[0], red[1]), fmaxf(red[2], red[3]));
        float e[4], s = 0.f;
#pragma unroll
        for (int j = 0; j < 4; ++j) { e[j] = __expf(l[j] - mx); s += e[j]; }
        s = wred_sum(s);
        __syncthreads();
        if ((tid & 63) == 0) red[4 + (tid >> 6)] = s;
        __syncthreads();
        s = red[4] + red[5] + red[6] + red[7];
        const float inv = 1.f / s;
#pragma unroll
        for (int j = 0; j < 4; ++j)
            posS[(long)n * NN_ + j * 256 + tid] = e[j] * inv;
    } else if (bid < 1536) {
        const int n4 = NB * NN_ * ND / 4;
        int i = (bid - 1024) * 256 + tid;
        for (; i < n4; i += 512 * 256) {
            float4 v = ((const float4*)x)[i];
            bf16x4 h, l;
            h[0] = (__bf16)v.x; l[0] = (__bf16)(v.x - (float)h[0]);
            h[1] = (__bf16)v.y; l[1] = (__bf16)(v.y - (float)h[1]);
            h[2] = (__bf16)v.z; l[2] = (__bf16)(v.z - (float)h[2]);
            h[3] = (__bf16)v.w; l[3] = (__bf16)(v.w - (float)h[3]);
            ((bf16x4*)Xh)[i] = h;
            ((bf16x4*)Xl)[i] = l;
        }
    } else if (bid < 2048) {
        __bf16 (*t)[72] = (__bf16(*)[72])sm;
        const int rem = bid - 1536;
        const int b = rem >> 6;
        const int m0 = (rem & 15) * 64, d0 = ((rem >> 4) & 3) * 64;
        const int c = tid & 15;
        const int r = tid >> 4;
#pragma unroll
        for (int p = 0; p < 4; ++p) {
            const int row = r + p * 16;
            const long gi = ((long)b * NN_ + m0 + row) * ND + d0 + c * 4;
            float4 v = *(const float4*)(y + gi);
            bf16x4 h, l;
            h[0] = (__bf16)v.x; l[0] = (__bf16)(v.x - (float)h[0]);
            h[1] = (__bf16)v.y; l[1] = (__bf16)(v.y - (float)h[1]);
            h[2] = (__bf16)v.z; l[2] = (__bf16)(v.z - (float)h[2]);
            h[3] = (__bf16)v.w; l[3] = (__bf16)(v.w - (float)h[3]);
            *(bf16x4*)(Yh + gi) = h;
            *(bf16x4*)(Yl + gi) = l;
            t[c * 4 + 0][row] = h[0]; t[c * 4 + 1][row] = h[1];
            t[c * 4 + 2][row] = h[2]; t[c * 4 + 3][row] = h[3];
        }
        __syncthreads();
#pragma unroll
        for (int p = 0; p < 4; ++p) {
            const int d = r + p * 16;
            bf16x4 o;
            o[0] = t[d][c * 4 + 0]; o[1] = t[d][c * 4 + 1];
            o[2] = t[d][c * 4 + 2]; o[3] = t[d][c * 4 + 3];
            *(bf16x4*)(yt + ((long)b * ND + d0 + d) * NN_ + m0 + c * 4) = o;
        }
    } else {
        const int n = bid - 2048, j = tid;
        float a1 = 0.f, a2 = 0.f;
        for (int c = 0; c < ND; ++c) {
            const float un = U[c * ND + n];
            const float uj = U[c * ND + j];
            a1 = fmaf(fabsf(S1[c]) * un, uj, a1);
            a2 = fmaf(fabsf(S2[c]) * un, uj, a2);
        }
        const __bf16 h1 = (__bf16)a1, h2 = (__bf16)a2;
        Mh[n * ND + j] = h1;           Ml[n * ND + j] = (__bf16)(a1 - (float)h1);
        Mh[65536 + n * ND + j] = h2;   Ml[65536 + n * ND + j] = (__bf16)(a2 - (float)h2);
    }
}

// ---------------- xs = x @ M_k (split x3, bf16 h/l out) ----------------
__global__ __launch_bounds__(256) void mgemm_xs(
    const __bf16* __restrict__ Ah, const __bf16* __restrict__ Al,
    const __bf16* __restrict__ Bh, const __bf16* __restrict__ Bl,
    __bf16* __restrict__ Ch, __bf16* __restrict__ Cl,
    int M, int N, int K, long sB1, long sC) {
    constexpr int BM = 128, BK = 32, BN = 64;
    __shared__ __bf16 As[2 * BM * BK];
    __shared__ __bf16 Bs[2 * BN * BK];

    const int z = blockIdx.z;
    Bh += (long)z * sB1; Bl += (long)z * sB1;

    const int tid = threadIdx.x;
    const int bm = blockIdx.y * BM, bn = blockIdx.x * BN;
    const int wave = tid >> 6, lane = tid & 63;
    const int wm = wave >> 1, wn = wave & 1;
    const int quad = lane >> 4, l16 = lane & 15;

    f32x4 acc[4][2];
#pragma unroll
    for (int i = 0; i < 4; ++i)
#pragma unroll
        for (int j = 0; j < 2; ++j) acc[i][j] = (f32x4){0.f, 0.f, 0.f, 0.f};

    const int srow = lane >> 2;
    const int slot = lane & 3;

    for (int k0 = 0; k0 < K; k0 += BK) {
        __syncthreads();
#pragma unroll
        for (int i = 0; i < 2; ++i) {
            const int r0 = wave * 32 + i * 16;
            const int row = r0 + srow;
            const int chunk = slot ^ ((row >> 1) & 3);
            const long g = (long)(bm + row) * K + k0 + chunk * 8;
            gl_lds(Ah + g, &As[r0 * 32]);
            gl_lds(Al + g, &As[BM * BK + r0 * 32]);
        }
        {
            const int r0 = wave * 16;
            const int row = r0 + srow;
            const int chunk = slot ^ ((row >> 1) & 3);
            const long g = (long)(bn + row) * K + k0 + chunk * 8;
            gl_lds(Bh + g, &Bs[r0 * 32]);
            gl_lds(Bl + g, &Bs[BN * BK + r0 * 32]);
        }
        __syncthreads();

        bf16x8 a_h[4], a_l[4], b_h[2], b_l[2];
#pragma unroll
        for (int mi = 0; mi < 4; ++mi) {
            const int row = wm * 64 + mi * 16 + l16;
            const int off = row * 32 + ((quad ^ ((row >> 1) & 3)) * 8);
            a_h[mi] = *(const bf16x8*)&As[off];
            a_l[mi] = *(const bf16x8*)&As[BM * BK + off];
        }
#pragma unroll
        for (int ni = 0; ni < 2; ++ni) {
            const int row = wn * 32 + ni * 16 + l16;
            const int off = row * 32 + ((quad ^ ((row >> 1) & 3)) * 8);
            b_h[ni] = *(const bf16x8*)&Bs[off];
            b_l[ni] = *(const bf16x8*)&Bs[BN * BK + off];
        }
#pragma unroll
        for (int mi = 0; mi < 4; ++mi)
#pragma unroll
            for (int ni = 0; ni < 2; ++ni) {
                acc[mi][ni] = __builtin_amdgcn_mfma_f32_16x16x32_bf16(
                    a_h[mi], b_h[ni], acc[mi][ni], 0, 0, 0);
                acc[mi][ni] = __builtin_amdgcn_mfma_f32_16x16x32_bf16(
                    a_h[mi], b_l[ni], acc[mi][ni], 0, 0, 0);
                acc[mi][ni] = __builtin_amdgcn_mfma_f32_16x16x32_bf16(
                    a_l[mi], b_h[ni], acc[mi][ni], 0, 0, 0);
            }
    }

    Ch += (long)z * sC; Cl += (long)z * sC;
#pragma unroll
    for (int mi = 0; mi < 4; ++mi) {
        const int row0 = bm + wm * 64 + mi * 16 + quad * 4;
#pragma unroll
        for (int ni = 0; ni < 2; ++ni) {
            const int col = bn + wn * 32 + ni * 16 + l16;
#pragma unroll
            for (int r = 0; r < 4; ++r) {
                const float v = acc[mi][ni][r];
                const long idx = (long)(row0 + r) * N + col;
                const __bf16 h = (__bf16)v;
                Ch[idx] = h;
                Cl[idx] = (__bf16)(v - (float)h);
            }
        }
    }
}

// ---------------- scores: S[z] = (XS_z @ Y_b^T)*alpha, fp32 out -------------
// z = b*2+br; A offset (z/2)*sA1 + (z%2)*sA2; B offset (z/2)*sB1; C z*sC.
__global__ __launch_bounds__(256) void mgemm_sc(
    const __bf16* __restrict__ Ah, const __bf16* __restrict__ Al,
    const __bf16* __restrict__ Bh, const __bf16* __restrict__ Bl,
    float* __restrict__ C, int N, int K,
    long sA1, long sA2, long sB1, long sC, float alpha) {
    constexpr int BM = 128, BK = 32, BN = 128;
    __shared__ __bf16 As[2 * BM * BK];
    __shared__ __bf16 Bs[2 * BN * BK];

    const int z = blockIdx.z;
    const long aoff = (long)(z >> 1) * sA1 + (long)(z & 1) * sA2;
    const long boff = (long)(z >> 1) * sB1;
    Ah += aoff; Al += aoff;
    Bh += boff; Bl += boff;

    const int tid = threadIdx.x;
    const int bm = blockIdx.y * BM, bn = blockIdx.x * BN;
    const int wave = tid >> 6, lane = tid & 63;
    const int wm = wave >> 1, wn = wave & 1;
    const int quad = lane >> 4, l16 = lane & 15;

    f32x4 acc[4][4];
#pragma unroll
    for (int i = 0; i < 4; ++i)
#pragma unroll
        for (int j = 0; j < 4; ++j) acc[i][j] = (f32x4){0.f, 0.f, 0.f, 0.f};

    const int srow = lane >> 2;
    const int slot = lane & 3;

    for (int k0 = 0; k0 < K; k0 += BK) {
        __syncthreads();
#pragma unroll
        for (int i = 0; i < 2; ++i) {
            const int r0 = wave * 32 + i * 16;
            const int row = r0 + srow;
            const int chunk = slot ^ ((row >> 1) & 3);
            const long ga = (long)(bm + row) * K + k0 + chunk * 8;
            gl_lds(Ah + ga, &As[r0 * 32]);
            gl_lds(Al + ga, &As[BM * BK + r0 * 32]);
            const long gb = (long)(bn + row) * K + k0 + chunk * 8;
            gl_lds(Bh + gb, &Bs[r0 * 32]);
            gl_lds(Bl + gb, &Bs[BN * BK + r0 * 32]);
        }
        __syncthreads();

        bf16x8 a_h[4], a_l[4], b_h[4], b_l[4];
#pragma unroll
        for (int mi = 0; mi < 4; ++mi) {
            const int row = wm * 64 + mi * 16 + l16;
            const int off = row * 32 + ((quad ^ ((row >> 1) & 3)) * 8);
            a_h[mi] = *(const bf16x8*)&As[off];
            a_l[mi] = *(const bf16x8*)&As[BM * BK + off];
        }
#pragma unroll
        for (int ni = 0; ni < 4; ++ni) {
            const int row = wn * 64 + ni * 16 + l16;
            const int off = row * 32 + ((quad ^ ((row >> 1) & 3)) * 8);
            b_h[ni] = *(const bf16x8*)&Bs[off];
            b_l[ni] = *(const bf16x8*)&Bs[BN * BK + off];
        }
#pragma unroll
        for (int mi = 0; mi < 4; ++mi)
#pragma unroll
            for (int ni = 0; ni < 4; ++ni) {
                acc[mi][ni] = __builtin_amdgcn_mfma_f32_16x16x32_bf16(
                    a_h[mi], b_h[ni], acc[mi][ni], 0, 0, 0);
                acc[mi][ni] = __builtin_amdgcn_mfma_f32_16x16x32_bf16(
                    a_h[mi], b_l[ni], acc[mi][ni], 0, 0, 0);
                acc[mi][ni] = __builtin_amdgcn_mfma_f32_16x16x32_bf16(
                    a_l[mi], b_h[ni], acc[mi][ni], 0, 0, 0);
            }
    }

    C += (long)z * sC;
#pragma unroll
    for (int mi = 0; mi < 4; ++mi) {
        const int row0 = bm + wm * 64 + mi * 16 + quad * 4;
#pragma unroll
        for (int ni = 0; ni < 4; ++ni) {
            const int col = bn + wn * 64 + ni * 16 + l16;
#pragma unroll
            for (int r = 0; r < 4; ++r)
                C[(long)(row0 + r) * NN_ + col] = acc[mi][ni][r] * alpha;
        }
    }
}

// ---------------- blendpv: softmax+blend+entropy+route + PV MFMA ------------
// Block 256 thr (4 waves) owns (b = blk&7, rows n0..n0+15). Wave w owns rows
// n0+w*4..+4 COMPLETELY -> softmax/entropy/route are wave-local shfl reductions
// (no barriers). Selected P -> LDS bf16 [16][1032]; one barrier; PV MFMA vs yt.
__global__ __launch_bounds__(256, 2) void blendpv_kernel(
    const float* __restrict__ S, const float* __restrict__ pos,
    const float* __restrict__ gating, const float* __restrict__ h_temp,
    const __bf16* __restrict__ yt, float* __restrict__ heat,
    float* __restrict__ out) {
    __shared__ __bf16 Pm[16][1032];

    const int b  = blockIdx.x & 7;
    const int n0 = (blockIdx.x >> 3) * 16;
    const int tid = threadIdx.x;
    const int wave = tid >> 6, lane = tid & 63;
    const int quad = lane >> 4, l16 = lane & 15;

    const float g = 1.f / (1.f + __expf(-gating[0]));
    const float cg = 1.f - g;
    const float ht = h_temp[0];

    const float* S0b = S + (long)(b * 2 + 0) * NN_ * NN_;
    const float* S1b = S + (long)(b * 2 + 1) * NN_ * NN_;

#pragma unroll
    for (int rr = 0; rr < 4; ++rr) {
        const int n = n0 + wave * 4 + rr;
        const float* r0p = S0b + (long)n * NN_;
        const float* r1p = S1b + (long)n * NN_;
        float4 a0[4], a1[4];
#pragma unroll
        for (int j = 0; j < 4; ++j) {
            a0[j] = *(const float4*)(r0p + j * 256 + lane * 4);
            a1[j] = *(const float4*)(r1p + j * 256 + lane * 4);
        }
        // row max (in-wave)
        float m0 = -3.4e38f, m1 = -3.4e38f;
#pragma unroll
        for (int j = 0; j < 4; ++j) {
            m0 = fmaxf(m0, fmaxf(fmaxf(a0[j].x, a0[j].y), fmaxf(a0[j].z, a0[j].w)));
            m1 = fmaxf(m1, fmaxf(fmaxf(a1[j].x, a1[j].y), fmaxf(a1[j].z, a1[j].w)));
        }
        m0 = wred_max(m0); m1 = wred_max(m1);
        // exp + sum
        float s0 = 0.f, s1 = 0.f;
#pragma unroll
        for (int j = 0; j < 4; ++j) {
            a0[j].x = __expf(a0[j].x - m0); a0[j].y = __expf(a0[j].y - m0);
            a0[j].z = __expf(a0[j].z - m0); a0[j].w = __expf(a0[j].w - m0);
            s0 += a0[j].x + a0[j].y + a0[j].z + a0[j].w;
            a1[j].x = __expf(a1[j].x - m1); a1[j].y = __expf(a1[j].y - m1);
            a1[j].z = __expf(a1[j].z - m1); a1[j].w = __expf(a1[j].w - m1);
            s1 += a1[j].x + a1[j].y + a1[j].z + a1[j].w;
        }
        s0 = wred_sum(s0); s1 = wred_sum(s1);
        const float i0 = 1.f / s0, i1 = 1.f / s1;
        // blend + entropy
        const float* pr = pos + (long)n * NN_;
        float e0 = 0.f, e1 = 0.f;
#pragma unroll
        for (int j = 0; j < 4; ++j) {
            const float4 pv = *(const float4*)(pr + j * 256 + lane * 4);
            a0[j].x = cg * a0[j].x * i0 + g * pv.x;
            a0[j].y = cg * a0[j].y * i0 + g * pv.y;
            a0[j].z = cg * a0[j].z * i0 + g * pv.z;
            a0[j].w = cg * a0[j].w * i0 + g * pv.w;
            a1[j].x = cg * a1[j].x * i1 + g * pv.x;
            a1[j].y = cg * a1[j].y * i1 + g * pv.y;
            a1[j].z = cg * a1[j].z * i1 + g * pv.z;
            a1[j].w = cg * a1[j].w * i1 + g * pv.w;
            e0 -= a0[j].x * __logf(a0[j].x + 1e-8f) + a0[j].y * __logf(a0[j].y + 1e-8f) +
                  a0[j].z * __logf(a0[j].z + 1e-8f) + a0[j].w * __logf(a0[j].w + 1e-8f);
            e1 -= a1[j].x * __logf(a1[j].x + 1e-8f) + a1[j].y * __logf(a1[j].y + 1e-8f) +
                  a1[j].z * __logf(a1[j].z + 1e-8f) + a1[j].w * __logf(a1[j].w + 1e-8f);
        }
        e0 = wred_sum(e0); e1 = wred_sum(e1);
        const float hm0 = 2.f - 2.f / (1.f + __expf(-ht * e0));
        const float hm1 = 2.f - 2.f / (1.f + __expf(-ht * e1));
        const bool fg = (hm0 >= hm1);
        if (lane == 0) heat[(long)b * NN_ + n] = fg ? hm0 : hm1;
        // selected P -> LDS (bf16)
        const int ri = wave * 4 + rr;
#pragma unroll
        for (int j = 0; j < 4; ++j) {
            const float4 v = fg ? a0[j] : a1[j];
            bf16x4 o;
            o[0] = (__bf16)v.x; o[1] = (__bf16)v.y;
            o[2] = (__bf16)v.z; o[3] = (__bf16)v.w;
            *(bf16x4*)&Pm[ri][j * 256 + lane * 4] = o;
        }
    }
    __syncthreads();

    // ---- PV: out[16 x 256] = P(LDS) @ yt^T ; wave d-slice 64 ----
    f32x4 oacc[4];
#pragma unroll
    for (int nd = 0; nd < 4; ++nd) oacc[nd] = (f32x4){0.f, 0.f, 0.f, 0.f};
    const __bf16* Bo = yt + ((long)b * ND + wave * 64) * NN_;
    for (int k0 = 0; k0 < NN_; k0 += 32) {
        bf16x8 pa = *(const bf16x8*)&Pm[l16][k0 + quad * 8];
#pragma unroll
        for (int nd = 0; nd < 4; ++nd) {
            bf16x8 bo = *(const bf16x8*)(Bo + (long)(nd * 16 + l16) * NN_ + k0 + quad * 8);
            oacc[nd] = __builtin_amdgcn_mfma_f32_16x16x32_bf16(pa, bo, oacc[nd], 0, 0, 0);
        }
    }
#pragma unroll
    for (int nd = 0; nd < 4; ++nd)
#pragma unroll
        for (int r = 0; r < 4; ++r)
            out[((long)b * NN_ + n0 + quad * 4 + r) * ND +
                wave * 64 + nd * 16 + l16] = oacc[nd][r];
}

extern "C" void kernel_launch(void* const* d_in, const int* in_sizes, int n_in,
                              void* d_out, int out_size, void* d_ws, size_t ws_size,
                              hipStream_t stream) {
    const float* x      = (const float*)d_in[0];
    const float* y      = (const float*)d_in[1];
    const float* coords = (const float*)d_in[2];
    const float* U      = (const float*)d_in[3];
    const float* S1p    = (const float*)d_in[4];
    const float* S2p    = (const float*)d_in[5];
    const float* gating = (const float*)d_in[6];
    const float* h_temp = (const float*)d_in[7];
    const float* p_temp = (const float*)d_in[8];
    const float* pos_emb= (const float*)d_in[9];

    float* out  = (float*)d_out;
    float* heat = out + (long)NB * NN_ * ND;

    // workspace (~105 MB)
    char* ws = (char*)d_ws;
    const long MB = 1 << 20;
    float*  Sf  = (float*)(ws);               // 64 MB [16][1024][1024]
    float*  pos = (float*)(ws + 64 * MB);     // 4 MB
    __bf16* Xh  = (__bf16*)(ws + 68 * MB);    // 4 MB
    __bf16* Xl  = (__bf16*)(ws + 72 * MB);    // 4 MB
    __bf16* XSh = (__bf16*)(ws + 76 * MB);    // 8 MB [2][8192][256]
    __bf16* XSl = (__bf16*)(ws + 84 * MB);    // 8 MB
    __bf16* yt  = (__bf16*)(ws + 92 * MB);    // 4 MB [8][256][1024]
    __bf16* Yh  = (__bf16*)(ws + 96 * MB);    // 4 MB
    __bf16* Yl  = (__bf16*)(ws + 100 * MB);   // 4 MB
    __bf16* Mh  = (__bf16*)(ws + 104 * MB);   // 256 KB [2][256][256]
    __bf16* Ml  = Mh + 2 * 65536;             // 256 KB

    const long ND2 = (long)NN_ * ND;          // 262144
    const long BND = (long)NB * ND2;          // 2097152

    // 1) fused prep
    prep_kernel<<<dim3(2304), 256, 0, stream>>>(
        coords, pos_emb, p_temp, x, y, U, S1p, S2p,
        pos, Xh, Xl, yt, Yh, Yl, Mh, Ml);

    // 2) xs_k = x @ M_k  -> XS [2][8192][256]
    mgemm_xs<<<dim3(4, 64, 2), 256, 0, stream>>>(
        Xh, Xl, Mh, Ml, XSh, XSl, NB * NN_, ND, ND, 65536, BND);

    // 3) scores: S[b*2+br] = (XS_br[b] @ Y[b]^T) * D^-0.5  (fp32, L3-resident)
    mgemm_sc<<<dim3(8, 8, NB * 2), 256, 0, stream>>>(
        XSh, XSl, Yh, Yl, Sf, NN_, ND,
        ND2, BND, ND2, (long)NN_ * NN_, 0.0625f);

    // 4) blend + entropy + route + PV
    blendpv_kernel<<<dim3(512), 256, 0, stream>>>(
        Sf, pos, gating, h_temp, yt, heat, out);

    (void)in_sizes; (void)n_in; (void)out_size; (void)ws_size;
}

// Round 10
// 211.390 us; speedup vs baseline: 1.2034x; 1.0242x over previous
//
#include <hip/hip_runtime.h>
#include <hip/hip_bf16.h>
#include <stdint.h>

// B=8, N=1024, D=256, fp32 in/out.
// R10: R9 pipeline; blendpv widened to 512 thr / 8 waves (4 waves/SIMD) to fix
// the measured latency-bound stall (R9: 52us @ 20% occupancy, 1.17 TB/s).
// 4 dispatches: prep -> xs mgemm -> scores mgemm -> blendpv.

#define NB 8
#define NN_ 1024
#define ND 256

typedef __bf16 bf16x8 __attribute__((ext_vector_type(8)));
typedef __bf16 bf16x4 __attribute__((ext_vector_type(4)));
typedef float f32x4 __attribute__((ext_vector_type(4)));

// ---------------- async global->LDS (16B per lane) ----------------
__device__ inline void gl_lds(const __bf16* g, __bf16* l) {
    auto gp = (const __attribute__((address_space(1))) uint32_t*)(uintptr_t)g;
    auto lp = (__attribute__((address_space(3))) uint32_t*)(uintptr_t)l;
    __builtin_amdgcn_global_load_lds(gp, lp, 16, 0, 0);
}

// ---------------- reductions ----------------
__device__ inline float wred_sum(float v) {
#pragma unroll
    for (int o = 32; o; o >>= 1) v += __shfl_xor(v, o, 64);
    return v;
}
__device__ inline float wred_max(float v) {
#pragma unroll
    for (int o = 32; o; o >>= 1) v = fmaxf(v, __shfl_xor(v, o, 64));
    return v;
}

// ---------------- fused prep: pos softmax | x split | y prep | build M ------
__global__ __launch_bounds__(256) void prep_kernel(
    const float* __restrict__ coords, const float* __restrict__ pos_emb,
    const float* __restrict__ p_temp, const float* __restrict__ x,
    const float* __restrict__ y, const float* __restrict__ U,
    const float* __restrict__ S1, const float* __restrict__ S2,
    float* __restrict__ posS, __bf16* __restrict__ Xh, __bf16* __restrict__ Xl,
    __bf16* __restrict__ yt, __bf16* __restrict__ Yh, __bf16* __restrict__ Yl,
    __bf16* __restrict__ Mh, __bf16* __restrict__ Ml) {
    __shared__ char sm[9216 + 64];
    const int bid = blockIdx.x;
    const int tid = threadIdx.x;

    if (bid < 1024) {
        float* red = (float*)sm;
        const int n = bid;
        const float pt = -fabsf(p_temp[0]);
        float pe[6];
#pragma unroll
        for (int c = 0; c < 6; ++c) pe[c] = pos_emb[n * 6 + c];
        const float* cr = coords + (long)n * NN_ * 6;
        float l[4];
#pragma unroll
        for (int j = 0; j < 4; ++j) {
            const int m = j * 256 + tid;
            const float2* cp = (const float2*)(cr + (long)m * 6);
            float2 c0 = cp[0], c1 = cp[1], c2 = cp[2];
            l[j] = pt * (c0.x * pe[0] + c0.y * pe[1] + c1.x * pe[2] +
                         c1.y * pe[3] + c2.x * pe[4] + c2.y * pe[5]);
        }
        float mx = fmaxf(fmaxf(l[0], l[1]), fmaxf(l[2], l[3]));
        mx = wred_max(mx);
        __syncthreads();
        if ((tid & 63) == 0) red[tid >> 6] = mx;
        __syncthreads();
        mx = fmaxf(fmaxf(red[0], red[1]), fmaxf(red[2], red[3]));
        float e[4], s = 0.f;
#pragma unroll
        for (int j = 0; j < 4; ++j) { e[j] = __expf(l[j] - mx); s += e[j]; }
        s = wred_sum(s);
        __syncthreads();
        if ((tid & 63) == 0) red[4 + (tid >> 6)] = s;
        __syncthreads();
        s = red[4] + red[5] + red[6] + red[7];
        const float inv = 1.f / s;
#pragma unroll
        for (int j = 0; j < 4; ++j)
            posS[(long)n * NN_ + j * 256 + tid] = e[j] * inv;
    } else if (bid < 1536) {
        const int n4 = NB * NN_ * ND / 4;
        int i = (bid - 1024) * 256 + tid;
        for (; i < n4; i += 512 * 256) {
            float4 v = ((const float4*)x)[i];
            bf16x4 h, l;
            h[0] = (__bf16)v.x; l[0] = (__bf16)(v.x - (float)h[0]);
            h[1] = (__bf16)v.y; l[1] = (__bf16)(v.y - (float)h[1]);
            h[2] = (__bf16)v.z; l[2] = (__bf16)(v.z - (float)h[2]);
            h[3] = (__bf16)v.w; l[3] = (__bf16)(v.w - (float)h[3]);
            ((bf16x4*)Xh)[i] = h;
            ((bf16x4*)Xl)[i] = l;
        }
    } else if (bid < 2048) {
        __bf16 (*t)[72] = (__bf16(*)[72])sm;
        const int rem = bid - 1536;
        const int b = rem >> 6;
        const int m0 = (rem & 15) * 64, d0 = ((rem >> 4) & 3) * 64;
        const int c = tid & 15;
        const int r = tid >> 4;
#pragma unroll
        for (int p = 0; p < 4; ++p) {
            const int row = r + p * 16;
            const long gi = ((long)b * NN_ + m0 + row) * ND + d0 + c * 4;
            float4 v = *(const float4*)(y + gi);
            bf16x4 h, l;
            h[0] = (__bf16)v.x; l[0] = (__bf16)(v.x - (float)h[0]);
            h[1] = (__bf16)v.y; l[1] = (__bf16)(v.y - (float)h[1]);
            h[2] = (__bf16)v.z; l[2] = (__bf16)(v.z - (float)h[2]);
            h[3] = (__bf16)v.w; l[3] = (__bf16)(v.w - (float)h[3]);
            *(bf16x4*)(Yh + gi) = h;
            *(bf16x4*)(Yl + gi) = l;
            t[c * 4 + 0][row] = h[0]; t[c * 4 + 1][row] = h[1];
            t[c * 4 + 2][row] = h[2]; t[c * 4 + 3][row] = h[3];
        }
        __syncthreads();
#pragma unroll
        for (int p = 0; p < 4; ++p) {
            const int d = r + p * 16;
            bf16x4 o;
            o[0] = t[d][c * 4 + 0]; o[1] = t[d][c * 4 + 1];
            o[2] = t[d][c * 4 + 2]; o[3] = t[d][c * 4 + 3];
            *(bf16x4*)(yt + ((long)b * ND + d0 + d) * NN_ + m0 + c * 4) = o;
        }
    } else {
        const int n = bid - 2048, j = tid;
        float a1 = 0.f, a2 = 0.f;
        for (int c = 0; c < ND; ++c) {
            const float un = U[c * ND + n];
            const float uj = U[c * ND + j];
            a1 = fmaf(fabsf(S1[c]) * un, uj, a1);
            a2 = fmaf(fabsf(S2[c]) * un, uj, a2);
        }
        const __bf16 h1 = (__bf16)a1, h2 = (__bf16)a2;
        Mh[n * ND + j] = h1;           Ml[n * ND + j] = (__bf16)(a1 - (float)h1);
        Mh[65536 + n * ND + j] = h2;   Ml[65536 + n * ND + j] = (__bf16)(a2 - (float)h2);
    }
}

// ---------------- xs = x @ M_k (split x3, bf16 h/l out) ----------------
__global__ __launch_bounds__(256) void mgemm_xs(
    const __bf16* __restrict__ Ah, const __bf16* __restrict__ Al,
    const __bf16* __restrict__ Bh, const __bf16* __restrict__ Bl,
    __bf16* __restrict__ Ch, __bf16* __restrict__ Cl,
    int M, int N, int K, long sB1, long sC) {
    constexpr int BM = 128, BK = 32, BN = 64;
    __shared__ __bf16 As[2 * BM * BK];
    __shared__ __bf16 Bs[2 * BN * BK];

    const int z = blockIdx.z;
    Bh += (long)z * sB1; Bl += (long)z * sB1;

    const int tid = threadIdx.x;
    const int bm = blockIdx.y * BM, bn = blockIdx.x * BN;
    const int wave = tid >> 6, lane = tid & 63;
    const int wm = wave >> 1, wn = wave & 1;
    const int quad = lane >> 4, l16 = lane & 15;

    f32x4 acc[4][2];
#pragma unroll
    for (int i = 0; i < 4; ++i)
#pragma unroll
        for (int j = 0; j < 2; ++j) acc[i][j] = (f32x4){0.f, 0.f, 0.f, 0.f};

    const int srow = lane >> 2;
    const int slot = lane & 3;

    for (int k0 = 0; k0 < K; k0 += BK) {
        __syncthreads();
#pragma unroll
        for (int i = 0; i < 2; ++i) {
            const int r0 = wave * 32 + i * 16;
            const int row = r0 + srow;
            const int chunk = slot ^ ((row >> 1) & 3);
            const long g = (long)(bm + row) * K + k0 + chunk * 8;
            gl_lds(Ah + g, &As[r0 * 32]);
            gl_lds(Al + g, &As[BM * BK + r0 * 32]);
        }
        {
            const int r0 = wave * 16;
            const int row = r0 + srow;
            const int chunk = slot ^ ((row >> 1) & 3);
            const long g = (long)(bn + row) * K + k0 + chunk * 8;
            gl_lds(Bh + g, &Bs[r0 * 32]);
            gl_lds(Bl + g, &Bs[BN * BK + r0 * 32]);
        }
        __syncthreads();

        bf16x8 a_h[4], a_l[4], b_h[2], b_l[2];
#pragma unroll
        for (int mi = 0; mi < 4; ++mi) {
            const int row = wm * 64 + mi * 16 + l16;
            const int off = row * 32 + ((quad ^ ((row >> 1) & 3)) * 8);
            a_h[mi] = *(const bf16x8*)&As[off];
            a_l[mi] = *(const bf16x8*)&As[BM * BK + off];
        }
#pragma unroll
        for (int ni = 0; ni < 2; ++ni) {
            const int row = wn * 32 + ni * 16 + l16;
            const int off = row * 32 + ((quad ^ ((row >> 1) & 3)) * 8);
            b_h[ni] = *(const bf16x8*)&Bs[off];
            b_l[ni] = *(const bf16x8*)&Bs[BN * BK + off];
        }
#pragma unroll
        for (int mi = 0; mi < 4; ++mi)
#pragma unroll
            for (int ni = 0; ni < 2; ++ni) {
                acc[mi][ni] = __builtin_amdgcn_mfma_f32_16x16x32_bf16(
                    a_h[mi], b_h[ni], acc[mi][ni], 0, 0, 0);
                acc[mi][ni] = __builtin_amdgcn_mfma_f32_16x16x32_bf16(
                    a_h[mi], b_l[ni], acc[mi][ni], 0, 0, 0);
                acc[mi][ni] = __builtin_amdgcn_mfma_f32_16x16x32_bf16(
                    a_l[mi], b_h[ni], acc[mi][ni], 0, 0, 0);
            }
    }

    Ch += (long)z * sC; Cl += (long)z * sC;
#pragma unroll
    for (int mi = 0; mi < 4; ++mi) {
        const int row0 = bm + wm * 64 + mi * 16 + quad * 4;
#pragma unroll
        for (int ni = 0; ni < 2; ++ni) {
            const int col = bn + wn * 32 + ni * 16 + l16;
#pragma unroll
            for (int r = 0; r < 4; ++r) {
                const float v = acc[mi][ni][r];
                const long idx = (long)(row0 + r) * N + col;
                const __bf16 h = (__bf16)v;
                Ch[idx] = h;
                Cl[idx] = (__bf16)(v - (float)h);
            }
        }
    }
}

// ---------------- scores: S[z] = (XS_z @ Y_b^T)*alpha, fp32 out -------------
__global__ __launch_bounds__(256) void mgemm_sc(
    const __bf16* __restrict__ Ah, const __bf16* __restrict__ Al,
    const __bf16* __restrict__ Bh, const __bf16* __restrict__ Bl,
    float* __restrict__ C, int N, int K,
    long sA1, long sA2, long sB1, long sC, float alpha) {
    constexpr int BM = 128, BK = 32, BN = 128;
    __shared__ __bf16 As[2 * BM * BK];
    __shared__ __bf16 Bs[2 * BN * BK];

    const int z = blockIdx.z;
    const long aoff = (long)(z >> 1) * sA1 + (long)(z & 1) * sA2;
    const long boff = (long)(z >> 1) * sB1;
    Ah += aoff; Al += aoff;
    Bh += boff; Bl += boff;

    const int tid = threadIdx.x;
    const int bm = blockIdx.y * BM, bn = blockIdx.x * BN;
    const int wave = tid >> 6, lane = tid & 63;
    const int wm = wave >> 1, wn = wave & 1;
    const int quad = lane >> 4, l16 = lane & 15;

    f32x4 acc[4][4];
#pragma unroll
    for (int i = 0; i < 4; ++i)
#pragma unroll
        for (int j = 0; j < 4; ++j) acc[i][j] = (f32x4){0.f, 0.f, 0.f, 0.f};

    const int srow = lane >> 2;
    const int slot = lane & 3;

    for (int k0 = 0; k0 < K; k0 += BK) {
        __syncthreads();
#pragma unroll
        for (int i = 0; i < 2; ++i) {
            const int r0 = wave * 32 + i * 16;
            const int row = r0 + srow;
            const int chunk = slot ^ ((row >> 1) & 3);
            const long ga = (long)(bm + row) * K + k0 + chunk * 8;
            gl_lds(Ah + ga, &As[r0 * 32]);
            gl_lds(Al + ga, &As[BM * BK + r0 * 32]);
            const long gb = (long)(bn + row) * K + k0 + chunk * 8;
            gl_lds(Bh + gb, &Bs[r0 * 32]);
            gl_lds(Bl + gb, &Bs[BN * BK + r0 * 32]);
        }
        __syncthreads();

        bf16x8 a_h[4], a_l[4], b_h[4], b_l[4];
#pragma unroll
        for (int mi = 0; mi < 4; ++mi) {
            const int row = wm * 64 + mi * 16 + l16;
            const int off = row * 32 + ((quad ^ ((row >> 1) & 3)) * 8);
            a_h[mi] = *(const bf16x8*)&As[off];
            a_l[mi] = *(const bf16x8*)&As[BM * BK + off];
        }
#pragma unroll
        for (int ni = 0; ni < 4; ++ni) {
            const int row = wn * 64 + ni * 16 + l16;
            const int off = row * 32 + ((quad ^ ((row >> 1) & 3)) * 8);
            b_h[ni] = *(const bf16x8*)&Bs[off];
            b_l[ni] = *(const bf16x8*)&Bs[BN * BK + off];
        }
#pragma unroll
        for (int mi = 0; mi < 4; ++mi)
#pragma unroll
            for (int ni = 0; ni < 4; ++ni) {
                acc[mi][ni] = __builtin_amdgcn_mfma_f32_16x16x32_bf16(
                    a_h[mi], b_h[ni], acc[mi][ni], 0, 0, 0);
                acc[mi][ni] = __builtin_amdgcn_mfma_f32_16x16x32_bf16(
                    a_h[mi], b_l[ni], acc[mi][ni], 0, 0, 0);
                acc[mi][ni] = __builtin_amdgcn_mfma_f32_16x16x32_bf16(
                    a_l[mi], b_h[ni], acc[mi][ni], 0, 0, 0);
            }
    }

    C += (long)z * sC;
#pragma unroll
    for (int mi = 0; mi < 4; ++mi) {
        const int row0 = bm + wm * 64 + mi * 16 + quad * 4;
#pragma unroll
        for (int ni = 0; ni < 4; ++ni) {
            const int col = bn + wn * 64 + ni * 16 + l16;
#pragma unroll
            for (int r = 0; r < 4; ++r)
                C[(long)(row0 + r) * NN_ + col] = acc[mi][ni][r] * alpha;
        }
    }
}

// ---------------- blendpv v2: 512 thr / 8 waves --------------------------
// Block owns (b = blk&7, rows n0..n0+15). Wave w owns rows n0+w*2..+2 fully ->
// softmax/entropy/route wave-local (no barriers). Selected P -> LDS bf16;
// one barrier; PV MFMA vs yt, wave d-slice 32.
__global__ __launch_bounds__(512, 4) void blendpv_kernel(
    const float* __restrict__ S, const float* __restrict__ pos,
    const float* __restrict__ gating, const float* __restrict__ h_temp,
    const __bf16* __restrict__ yt, float* __restrict__ heat,
    float* __restrict__ out) {
    __shared__ __bf16 Pm[16][1032];

    const int b  = blockIdx.x & 7;
    const int n0 = (blockIdx.x >> 3) * 16;
    const int tid = threadIdx.x;
    const int wave = tid >> 6, lane = tid & 63;
    const int quad = lane >> 4, l16 = lane & 15;

    const float g = 1.f / (1.f + __expf(-gating[0]));
    const float cg = 1.f - g;
    const float ht = h_temp[0];

    const float* S0b = S + (long)(b * 2 + 0) * NN_ * NN_;
    const float* S1b = S + (long)(b * 2 + 1) * NN_ * NN_;

#pragma unroll
    for (int rr = 0; rr < 2; ++rr) {
        const int n = n0 + wave * 2 + rr;
        const float* r0p = S0b + (long)n * NN_;
        const float* r1p = S1b + (long)n * NN_;
        float4 a0[4], a1[4];
#pragma unroll
        for (int j = 0; j < 4; ++j) {
            a0[j] = *(const float4*)(r0p + j * 256 + lane * 4);
            a1[j] = *(const float4*)(r1p + j * 256 + lane * 4);
        }
        // row max (in-wave)
        float m0 = -3.4e38f, m1 = -3.4e38f;
#pragma unroll
        for (int j = 0; j < 4; ++j) {
            m0 = fmaxf(m0, fmaxf(fmaxf(a0[j].x, a0[j].y), fmaxf(a0[j].z, a0[j].w)));
            m1 = fmaxf(m1, fmaxf(fmaxf(a1[j].x, a1[j].y), fmaxf(a1[j].z, a1[j].w)));
        }
        m0 = wred_max(m0); m1 = wred_max(m1);
        // exp + sum
        float s0 = 0.f, s1 = 0.f;
#pragma unroll
        for (int j = 0; j < 4; ++j) {
            a0[j].x = __expf(a0[j].x - m0); a0[j].y = __expf(a0[j].y - m0);
            a0[j].z = __expf(a0[j].z - m0); a0[j].w = __expf(a0[j].w - m0);
            s0 += a0[j].x + a0[j].y + a0[j].z + a0[j].w;
            a1[j].x = __expf(a1[j].x - m1); a1[j].y = __expf(a1[j].y - m1);
            a1[j].z = __expf(a1[j].z - m1); a1[j].w = __expf(a1[j].w - m1);
            s1 += a1[j].x + a1[j].y + a1[j].z + a1[j].w;
        }
        s0 = wred_sum(s0); s1 = wred_sum(s1);
        const float i0 = 1.f / s0, i1 = 1.f / s1;
        // blend + entropy
        const float* pr = pos + (long)n * NN_;
        float e0 = 0.f, e1 = 0.f;
#pragma unroll
        for (int j = 0; j < 4; ++j) {
            const float4 pv = *(const float4*)(pr + j * 256 + lane * 4);
            a0[j].x = cg * a0[j].x * i0 + g * pv.x;
            a0[j].y = cg * a0[j].y * i0 + g * pv.y;
            a0[j].z = cg * a0[j].z * i0 + g * pv.z;
            a0[j].w = cg * a0[j].w * i0 + g * pv.w;
            a1[j].x = cg * a1[j].x * i1 + g * pv.x;
            a1[j].y = cg * a1[j].y * i1 + g * pv.y;
            a1[j].z = cg * a1[j].z * i1 + g * pv.z;
            a1[j].w = cg * a1[j].w * i1 + g * pv.w;
            e0 -= a0[j].x * __logf(a0[j].x + 1e-8f) + a0[j].y * __logf(a0[j].y + 1e-8f) +
                  a0[j].z * __logf(a0[j].z + 1e-8f) + a0[j].w * __logf(a0[j].w + 1e-8f);
            e1 -= a1[j].x * __logf(a1[j].x + 1e-8f) + a1[j].y * __logf(a1[j].y + 1e-8f) +
                  a1[j].z * __logf(a1[j].z + 1e-8f) + a1[j].w * __logf(a1[j].w + 1e-8f);
        }
        e0 = wred_sum(e0); e1 = wred_sum(e1);
        const float hm0 = 2.f - 2.f / (1.f + __expf(-ht * e0));
        const float hm1 = 2.f - 2.f / (1.f + __expf(-ht * e1));
        const bool fg = (hm0 >= hm1);
        if (lane == 0) heat[(long)b * NN_ + n] = fg ? hm0 : hm1;
        // selected P -> LDS (bf16)
        const int ri = wave * 2 + rr;
#pragma unroll
        for (int j = 0; j < 4; ++j) {
            const float4 v = fg ? a0[j] : a1[j];
            bf16x4 o;
            o[0] = (__bf16)v.x; o[1] = (__bf16)v.y;
            o[2] = (__bf16)v.z; o[3] = (__bf16)v.w;
            *(bf16x4*)&Pm[ri][j * 256 + lane * 4] = o;
        }
    }
    __syncthreads();

    // ---- PV: out[16 x 256] = P(LDS) @ yt^T ; wave d-slice 32 ----
    f32x4 oacc[2];
#pragma unroll
    for (int nd = 0; nd < 2; ++nd) oacc[nd] = (f32x4){0.f, 0.f, 0.f, 0.f};
    const __bf16* Bo = yt + ((long)b * ND + wave * 32) * NN_;
    for (int k0 = 0; k0 < NN_; k0 += 32) {
        bf16x8 pa = *(const bf16x8*)&Pm[l16][k0 + quad * 8];
#pragma unroll
        for (int nd = 0; nd < 2; ++nd) {
            bf16x8 bo = *(const bf16x8*)(Bo + (long)(nd * 16 + l16) * NN_ + k0 + quad * 8);
            oacc[nd] = __builtin_amdgcn_mfma_f32_16x16x32_bf16(pa, bo, oacc[nd], 0, 0, 0);
        }
    }
#pragma unroll
    for (int nd = 0; nd < 2; ++nd)
#pragma unroll
        for (int r = 0; r < 4; ++r)
            out[((long)b * NN_ + n0 + quad * 4 + r) * ND +
                wave * 32 + nd * 16 + l16] = oacc[nd][r];
}

extern "C" void kernel_launch(void* const* d_in, const int* in_sizes, int n_in,
                              void* d_out, int out_size, void* d_ws, size_t ws_size,
                              hipStream_t stream) {
    const float* x      = (const float*)d_in[0];
    const float* y      = (const float*)d_in[1];
    const float* coords = (const float*)d_in[2];
    const float* U      = (const float*)d_in[3];
    const float* S1p    = (const float*)d_in[4];
    const float* S2p    = (const float*)d_in[5];
    const float* gating = (const float*)d_in[6];
    const float* h_temp = (const float*)d_in[7];
    const float* p_temp = (const float*)d_in[8];
    const float* pos_emb= (const float*)d_in[9];

    float* out  = (float*)d_out;
    float* heat = out + (long)NB * NN_ * ND;

    // workspace (~105 MB)
    char* ws = (char*)d_ws;
    const long MB = 1 << 20;
    float*  Sf  = (float*)(ws);               // 64 MB [16][1024][1024]
    float*  pos = (float*)(ws + 64 * MB);     // 4 MB
    __bf16* Xh  = (__bf16*)(ws + 68 * MB);    // 4 MB
    __bf16* Xl  = (__bf16*)(ws + 72 * MB);    // 4 MB
    __bf16* XSh = (__bf16*)(ws + 76 * MB);    // 8 MB [2][8192][256]
    __bf16* XSl = (__bf16*)(ws + 84 * MB);    // 8 MB
    __bf16* yt  = (__bf16*)(ws + 92 * MB);    // 4 MB [8][256][1024]
    __bf16* Yh  = (__bf16*)(ws + 96 * MB);    // 4 MB
    __bf16* Yl  = (__bf16*)(ws + 100 * MB);   // 4 MB
    __bf16* Mh  = (__bf16*)(ws + 104 * MB);   // 256 KB [2][256][256]
    __bf16* Ml  = Mh + 2 * 65536;             // 256 KB

    const long ND2 = (long)NN_ * ND;          // 262144
    const long BND = (long)NB * ND2;          // 2097152

    // 1) fused prep
    prep_kernel<<<dim3(2304), 256, 0, stream>>>(
        coords, pos_emb, p_temp, x, y, U, S1p, S2p,
        pos, Xh, Xl, yt, Yh, Yl, Mh, Ml);

    // 2) xs_k = x @ M_k  -> XS [2][8192][256]
    mgemm_xs<<<dim3(4, 64, 2), 256, 0, stream>>>(
        Xh, Xl, Mh, Ml, XSh, XSl, NB * NN_, ND, ND, 65536, BND);

    // 3) scores: S[b*2+br] = (XS_br[b] @ Y[b]^T) * D^-0.5  (fp32, L3-resident)
    mgemm_sc<<<dim3(8, 8, NB * 2), 256, 0, stream>>>(
        XSh, XSl, Yh, Yl, Sf, NN_, ND,
        ND2, BND, ND2, (long)NN_ * NN_, 0.0625f);

    // 4) blend + entropy + route + PV
    blendpv_kernel<<<dim3(512), 512, 0, stream>>>(
        Sf, pos, gating, h_temp, yt, heat, out);

    (void)in_sizes; (void)n_in; (void)out_size; (void)ws_size;
}